// Round 1
// baseline (1485.315 us; speedup 1.0000x reference)
//
#include <hip/hip_runtime.h>
#include <cmath>

#define NT 256
#define BT 128

// ---------------- ws float-offsets for constant tables ----------------
#define OFF_W60  0          // 19*60 complex  (e^{-2pi i (r-9) a/60})
#define OFF_E20  2280       // 20 complex     (e^{+2pi i t/20})
#define OFF_E12  2320       // 12 complex
#define OFF_W2J  2344       // 12 floats      (qw(B2))
#define OFF_DM1  2356       // 100*60         (w_in[j]*d^l_{m0}(beta_in_j))
#define OFF_Y1B  8356       // 100*24 complex
#define OFF_D1   13156      // 26600          (d^l at 20 beta1 points)
#define OFF_DM2  39756      // 286*20         (w1[j]*d^l_{mn}(beta1_j))
#define OFF_Y2B  45476      // 286*192 complex
#define OFF_D2   155300     // 3432           (d^l at 12 beta2 points)
#define OFF_END  158732
#define N_INIT   100248

__constant__ int c_ZB1[10]   = {0,1,10,35,84,165,286,455,680,969};
__constant__ int c_ZB2[6]    = {0,1,10,35,84,165};
__constant__ int c_D1OFF[10] = {0,20,200,700,1680,3300,5720,9100,13600,19380};
__constant__ int c_D2OFF[6]  = {0,12,120,420,1008,1980};

// ---------------- fp64 helpers for the init kernel ----------------
__device__ inline double dipow(double x, int e) {
    double r = 1.0;
    for (int i = 0; i < e; ++i) r *= x;
    return r;
}

// d^l_{mp,m}(beta) = <mp| exp(-i beta Jy) |m>, Wigner factorial formula
__device__ double wigd(const double* F, int l, int mp, int m, double beta) {
    double cb = cos(beta * 0.5), sb = sin(beta * 0.5);
    int smin = m - mp; if (smin < 0) smin = 0;
    int smax = l + m;  if (l - mp < smax) smax = l - mp;
    double pref = sqrt(F[l+mp] * F[l-mp] * F[l+m] * F[l-m]);
    double sum = 0.0;
    for (int s = smin; s <= smax; ++s) {
        double t = pref / (F[l+m-s] * F[s] * F[mp-m+s] * F[l-mp-s]);
        t *= dipow(cb, 2*l + m - mp - 2*s) * dipow(sb, mp - m + 2*s);
        sum += ((mp - m + s) & 1) ? -t : t;
    }
    return sum;
}

// Driscoll-Healy quadrature weight j of bandwidth bnd
__device__ double qwj(int bnd, int j) {
    const double PI = 3.14159265358979323846;
    double theta = PI * (2*j + 1) / (4.0 * bnd);
    double s = 0.0;
    for (int k = 0; k < bnd; ++k) s += sin(theta * (2*k + 1)) / (2*k + 1);
    return 2.0 / bnd * sin(theta) * s;
}

// ---------------- init: build all constant tables on device ----------------
__global__ void k_init(float* __restrict__ ws) {
    int idx = blockIdx.x * blockDim.x + threadIdx.x;
    if (idx >= N_INIT) return;
    double F[20];
    F[0] = 1.0;
    #pragma unroll
    for (int i = 1; i < 20; ++i) F[i] = F[i-1] * i;
    const double PI = 3.14159265358979323846;

    if (idx < 1140) {                       // W60[r][a], m = r-9
        int r = idx / 60, a = idx % 60;
        double ang = -2.0 * PI * (double)((r - 9) * a) / 60.0;
        ws[OFF_W60 + 2*idx]     = (float)cos(ang);
        ws[OFF_W60 + 2*idx + 1] = (float)sin(ang);
    } else if (idx < 1160) {                // E20[t] = e^{2pi i t/20}
        int t = idx - 1140;
        double ang = 2.0 * PI * t / 20.0;
        ws[OFF_E20 + 2*t]     = (float)cos(ang);
        ws[OFF_E20 + 2*t + 1] = (float)sin(ang);
    } else if (idx < 1172) {                // E12
        int t = idx - 1160;
        double ang = 2.0 * PI * t / 12.0;
        ws[OFF_E12 + 2*t]     = (float)cos(ang);
        ws[OFF_E12 + 2*t + 1] = (float)sin(ang);
    } else if (idx < 1184) {                // W2J
        int j = idx - 1172;
        ws[OFF_W2J + j] = (float)qwj(6, j);
    } else if (idx < 7184) {                // DM1[k][j]
        int e = idx - 1184; int k = e / 60, j = e % 60;
        int l = 0; while ((l + 1) * (l + 1) <= k) ++l;
        int m = k - l*l - l;
        double beta = PI * (2*j + 1) / 120.0;
        ws[OFF_DM1 + e] = (float)(qwj(30, j) * wigd(F, l, m, 0, beta));
    } else if (idx < 9584) {                // Y1B[k][g] (s2 grid 3x8)
        int e = idx - 7184; int k = e / 24, g = e % 24;
        int l = 0; while ((l + 1) * (l + 1) <= k) ++l;
        int m = k - l*l - l;
        int bi = g / 8, ai = g % 8;
        double beta  = (bi + 1) * (PI / 8.0) / 3.0;
        double alpha = 2.0 * PI * ai / 8.0;
        double d = wigd(F, l, m, 0, beta);
        double ph = -(double)m * alpha;
        ws[OFF_Y1B + 2*e]     = (float)(d * cos(ph));
        ws[OFF_Y1B + 2*e + 1] = (float)(d * sin(ph));
    } else if (idx < 36184) {               // D1 at beta1 grid (20)
        int e = idx - 9584;
        int l = 0; while (l < 9 && e >= c_D1OFF[l+1]) ++l;
        int L = 2*l + 1, loc = e - c_D1OFF[l];
        int j = loc / (L*L), rem = loc % (L*L), mi = rem / L, ni = rem % L;
        double beta = PI * (2*j + 1) / 40.0;
        ws[OFF_D1 + e] = (float)wigd(F, l, mi - l, ni - l, beta);
    } else if (idx < 41904) {               // DM2[k2][j]
        int e = idx - 36184; int k2 = e / 20, j = e % 20;
        int l = 0; while (l < 5 && k2 >= c_ZB2[l+1]) ++l;
        int L = 2*l + 1, loc = k2 - c_ZB2[l];
        int mi = loc / L, ni = loc % L;
        double beta = PI * (2*j + 1) / 40.0;
        ws[OFF_DM2 + e] = (float)(qwj(10, j) * wigd(F, l, mi - l, ni - l, beta));
    } else if (idx < 96816) {               // Y2B[k2][g] (so3 grid 3x8x8)
        int e = idx - 41904; int k2 = e / 192, g = e % 192;
        int l = 0; while (l < 5 && k2 >= c_ZB2[l+1]) ++l;
        int L = 2*l + 1, loc = k2 - c_ZB2[l];
        int m = loc / L - l, n = loc % L - l;
        int bi = g / 64, ai = (g / 8) % 8, ci = g % 8;
        double beta  = (bi + 1) * (PI / 8.0) / 3.0;
        double alpha = 2.0 * PI * ai / 8.0;
        double gamma = (-2.0 * PI + ci * (PI / 2.0)) - alpha;
        double d = wigd(F, l, m, n, beta);
        double ph = -((double)m * alpha + (double)n * gamma);
        ws[OFF_Y2B + 2*e]     = (float)(d * cos(ph));
        ws[OFF_Y2B + 2*e + 1] = (float)(d * sin(ph));
    } else {                                // D2 at beta2 grid (12)
        int e = idx - 96816;
        int l = 0; while (l < 5 && e >= c_D2OFF[l+1]) ++l;
        int L = 2*l + 1, loc = e - c_D2OFF[l];
        int j = loc / (L*L), rem = loc % (L*L), mi = rem / L, ni = rem % L;
        double beta = PI * (2*j + 1) / 24.0;
        ws[OFF_D2 + e] = (float)wigd(F, l, mi - l, ni - l, beta);
    }
}

// ---------------- pipeline kernels ----------------

// xh[b][j][r] = (1/60) sum_a x[b,0,j,a] e^{-2pi i (r-9) a/60}
__global__ void k_dft_alpha(const float* __restrict__ x, const float2* __restrict__ W60,
                            float2* __restrict__ xh) {
    int idx = blockIdx.x * blockDim.x + threadIdx.x;
    if (idx >= BT * 60 * 19) return;
    int r = idx % 19;
    int j = (idx / 19) % 60;
    int b = idx / (19 * 60);
    const float* xr = x + (b * 60 + j) * 60;
    const float2* wr = W60 + r * 60;
    float re = 0.f, im = 0.f;
    for (int a = 0; a < 60; ++a) {
        float v = xr[a];
        float2 w = wr[a];
        re += v * w.x; im += v * w.y;
    }
    xh[idx] = make_float2(re * (1.f / 60.f), im * (1.f / 60.f));
}

// X[k][b] = sum_j DM1[k][j] * xh[b][j][m_k+9]
__global__ void k_X1(const float2* __restrict__ xh, const float* __restrict__ DM1,
                     float2* __restrict__ X) {
    int idx = blockIdx.x * blockDim.x + threadIdx.x;
    if (idx >= 100 * BT) return;
    int b = idx % BT, k = idx / BT;
    int l = 0; while ((l + 1) * (l + 1) <= k) ++l;
    int r = (k - l*l - l) + 9;
    float re = 0.f, im = 0.f;
    for (int j = 0; j < 60; ++j) {
        float d = DM1[k * 60 + j];
        float2 v = xh[(b * 60 + j) * 19 + r];
        re += d * v.x; im += d * v.y;
    }
    X[k * BT + b] = make_float2(re, im);
}

// Yk1[k][o] = SC1 * sum_g Y1B[k][g] * kernel1[0,o,g]
__global__ void k_Yk1(const float* __restrict__ k1, const float2* __restrict__ Y1B,
                      float2* __restrict__ Yk1) {
    int idx = blockIdx.x * blockDim.x + threadIdx.x;
    if (idx >= 100 * 20) return;
    int o = idx % 20, k = idx / 20;
    float re = 0.f, im = 0.f;
    for (int g = 0; g < 24; ++g) {
        float2 y = Y1B[k * 24 + g];
        float w = k1[o * 24 + g];
        re += y.x * w; im += y.y * w;
    }
    const float SC1 = 0.20412414523193154f;  // 1/sqrt(24)
    Yk1[idx] = make_float2(re * SC1, im * SC1);
}

// Yk2[k2][o][i] = SC2 * sum_g Y2B[k2][g] * kernel2[i,o,g]   (transposed layout [k2][o][i])
__global__ void k_Yk2(const float* __restrict__ k2in, const float2* __restrict__ Y2B,
                      float2* __restrict__ Yk2) {
    int idx = blockIdx.x * blockDim.x + threadIdx.x;
    if (idx >= 286 * 40 * 20) return;
    int i = idx % 20, o = (idx / 20) % 40, k = idx / 800;
    const float* kp = k2in + (i * 40 + o) * 192;
    const float2* yp = Y2B + k * 192;
    float re = 0.f, im = 0.f;
    for (int g = 0; g < 192; ++g) {
        float2 y = yp[g];
        float w = kp[g];
        re += y.x * w; im += y.y * w;
    }
    const float SC2 = 0.016137430609197573f; // 1/sqrt(192*20)
    Yk2[(k * 40 + o) * 20 + i] = make_float2(re * SC2, im * SC2);
}

// Stage 1: one block per (b, f1). Produces X2[k2][b][f1] (k2<286), folding:
// outer products Z, per-beta1 Wigner contraction, 20x20 inverse DFT, ReLU,
// band-limited forward DFT, and beta1-quadrature projection DM2.
__global__ __launch_bounds__(NT) void k_stage1(
    const float2* __restrict__ X, const float2* __restrict__ Yk1,
    const float* __restrict__ cD1, const float* __restrict__ cDM2,
    const float2* __restrict__ cE20, float2* __restrict__ X2) {
    const int b = blockIdx.x % BT;
    const int f = blockIdx.x / BT;   // 0..19
    const int tid = threadIdx.x;

    __shared__ float2 sZ[1330];
    __shared__ float2 sS[361];
    __shared__ float2 sU[380];
    __shared__ float  sx1[400];
    __shared__ float2 sV[220];
    __shared__ float2 sG[121];
    __shared__ float2 sX2[286];

    // Z[(l,m,n)] = X[(l,m)][b] * conj(Yk1[(l,n)][f])
    for (int t = tid; t < 1330; t += NT) {
        int l = 0; while (l < 9 && t >= c_ZB1[l+1]) ++l;
        int L = 2*l + 1, loc = t - c_ZB1[l];
        int mi = loc / L, ni = loc % L;
        float2 a = X[(l*l + mi) * BT + b];
        float2 y = Yk1[(l*l + ni) * 20 + f];
        sZ[t] = make_float2(a.x * y.x + a.y * y.y, a.y * y.x - a.x * y.y);
    }
    for (int t = tid; t < 286; t += NT) sX2[t] = make_float2(0.f, 0.f);
    __syncthreads();

    for (int j = 0; j < 20; ++j) {
        // Ssum[m][n] = sum_l (2l+1) d^l_j[m,n] Z[l,m,n],  m,n in [-9,9]
        for (int idx = tid; idx < 361; idx += NT) {
            int mi = idx / 19, ni = idx % 19;
            int m = mi - 9, n = ni - 9;
            int am = m < 0 ? -m : m, an = n < 0 ? -n : n;
            int lmin = am > an ? am : an;
            float re = 0.f, im = 0.f;
            for (int l = lmin; l < 10; ++l) {
                int L = 2*l + 1;
                int o = (m + l) * L + (n + l);
                float dv = cD1[c_D1OFF[l] + j * L * L + o] * (float)L;
                float2 z = sZ[c_ZB1[l] + o];
                re += dv * z.x; im += dv * z.y;
            }
            sS[idx] = make_float2(re, im);
        }
        __syncthreads();
        // U[m][c] = sum_n Ssum[m][n] e^{+2pi i n c/20}
        for (int idx = tid; idx < 380; idx += NT) {
            int mi = idx / 20, c = idx % 20;
            float re = 0.f, im = 0.f;
            for (int ni = 0; ni < 19; ++ni) {
                int n = ni - 9;
                int ph = (n * c) % 20; if (ph < 0) ph += 20;
                float2 e = cE20[ph];
                float2 s = sS[mi * 19 + ni];
                re += s.x * e.x - s.y * e.y;
                im += s.x * e.y + s.y * e.x;
            }
            sU[mi * 20 + c] = make_float2(re, im);
        }
        __syncthreads();
        // x1[a][c] = relu(Re sum_m U[m][c] e^{+2pi i m a/20})
        for (int idx = tid; idx < 400; idx += NT) {
            int a = idx / 20, c = idx % 20;
            float acc = 0.f;
            for (int mi = 0; mi < 19; ++mi) {
                int m = mi - 9;
                int ph = (m * a) % 20; if (ph < 0) ph += 20;
                float2 e = cE20[ph];
                float2 u = sU[mi * 20 + c];
                acc += u.x * e.x - u.y * e.y;
            }
            sx1[idx] = acc > 0.f ? acc : 0.f;
        }
        __syncthreads();
        // V[a][nn] = sum_c x1[a][c] e^{-2pi i nn c/20},  nn in [-5,5]
        for (int idx = tid; idx < 220; idx += NT) {
            int a = idx / 11, ri = idx % 11;
            int nn = ri - 5;
            float re = 0.f, im = 0.f;
            for (int c = 0; c < 20; ++c) {
                float v = sx1[a * 20 + c];
                int ph = (-nn * c) % 20; if (ph < 0) ph += 20;
                float2 e = cE20[ph];
                re += v * e.x; im += v * e.y;
            }
            sV[idx] = make_float2(re, im);
        }
        __syncthreads();
        // G[mm][nn] = sum_a V[a][nn] e^{-2pi i mm a/20}
        for (int idx = tid; idx < 121; idx += NT) {
            int mi2 = idx / 11, ri = idx % 11;
            int mm = mi2 - 5;
            float re = 0.f, im = 0.f;
            for (int a = 0; a < 20; ++a) {
                int ph = (-mm * a) % 20; if (ph < 0) ph += 20;
                float2 e = cE20[ph];
                float2 v = sV[a * 11 + ri];
                re += v.x * e.x - v.y * e.y;
                im += v.x * e.y + v.y * e.x;
            }
            sG[idx] = make_float2(re, im);
        }
        __syncthreads();
        // X2acc[k2] += DM2[k2][j] * G[m(k2)][n(k2)]
        for (int k2 = tid; k2 < 286; k2 += NT) {
            int l = 0; while (l < 5 && k2 >= c_ZB2[l+1]) ++l;
            int L = 2*l + 1, loc = k2 - c_ZB2[l];
            int m = loc / L - l, n = loc % L - l;
            float dm = cDM2[k2 * 20 + j];
            float2 g = sG[(m + 5) * 11 + (n + 5)];
            sX2[k2].x += dm * g.x;
            sX2[k2].y += dm * g.y;
        }
        __syncthreads();
    }
    for (int k2 = tid; k2 < 286; k2 += NT) {
        X2[k2 * (BT * 20) + b * 20 + f] =
            make_float2(sX2[k2].x * (1.f / 400.f), sX2[k2].y * (1.f / 400.f));
    }
}

// Stage 2: one block per (b, f2). SO(3) correlation + per-beta2 contraction +
// 12x12 inverse DFT + ReLU + quadrature integral -> feat[b][f2]
__global__ __launch_bounds__(NT) void k_stage2(
    const float2* __restrict__ X2, const float2* __restrict__ Yk2,
    const float* __restrict__ cD2, const float2* __restrict__ cE12,
    const float* __restrict__ cW2J, float* __restrict__ feat) {
    const int b = blockIdx.x % BT;
    const int o = blockIdx.x / BT;   // 0..39
    const int tid = threadIdx.x;

    __shared__ float2 sX2b[286 * 20];
    __shared__ float2 sZ[286];
    __shared__ float2 sS[121];
    __shared__ float2 sU[132];
    __shared__ float  sred[NT];

    for (int t = tid; t < 286 * 20; t += NT)
        sX2b[t] = X2[(t / 20) * (BT * 20) + b * 20 + (t % 20)];
    __syncthreads();

    // Z[(l,m,n)] = sum_k sum_i X2[(l,m,k)][b][i] * conj(Yk2[(l,n,k)][o][i])
    for (int t = tid; t < 286; t += NT) {
        int l = 0; while (l < 5 && t >= c_ZB2[l+1]) ++l;
        int L = 2*l + 1, loc = t - c_ZB2[l];
        int mi = loc / L, ni = loc % L;
        float re = 0.f, im = 0.f;
        for (int k = 0; k < L; ++k) {
            const float2* xp = &sX2b[(c_ZB2[l] + mi * L + k) * 20];
            const float2* yp = Yk2 + ((c_ZB2[l] + ni * L + k) * 40 + o) * 20;
            for (int i = 0; i < 20; ++i) {
                float2 a = xp[i], y = yp[i];
                re += a.x * y.x + a.y * y.y;
                im += a.y * y.x - a.x * y.y;
            }
        }
        sZ[t] = make_float2(re, im);
    }
    __syncthreads();

    float facc = 0.f;
    for (int j = 0; j < 12; ++j) {
        for (int idx = tid; idx < 121; idx += NT) {
            int mi = idx / 11, ni = idx % 11;
            int m = mi - 5, n = ni - 5;
            int am = m < 0 ? -m : m, an = n < 0 ? -n : n;
            int lmin = am > an ? am : an;
            float re = 0.f, im = 0.f;
            for (int l = lmin; l < 6; ++l) {
                int L = 2*l + 1;
                int off = (m + l) * L + (n + l);
                float dv = cD2[c_D2OFF[l] + j * L * L + off] * (float)L;
                float2 z = sZ[c_ZB2[l] + off];
                re += dv * z.x; im += dv * z.y;
            }
            sS[idx] = make_float2(re, im);
        }
        __syncthreads();
        for (int idx = tid; idx < 132; idx += NT) {
            int mi = idx / 12, c = idx % 12;
            float re = 0.f, im = 0.f;
            for (int ni = 0; ni < 11; ++ni) {
                int n = ni - 5;
                int ph = (n * c) % 12; if (ph < 0) ph += 12;
                float2 e = cE12[ph];
                float2 s = sS[mi * 11 + ni];
                re += s.x * e.x - s.y * e.y;
                im += s.x * e.y + s.y * e.x;
            }
            sU[mi * 12 + c] = make_float2(re, im);
        }
        __syncthreads();
        float wj = cW2J[j];
        for (int idx = tid; idx < 144; idx += NT) {
            int a = idx / 12, c = idx % 12;
            float acc = 0.f;
            for (int mi = 0; mi < 11; ++mi) {
                int m = mi - 5;
                int ph = (m * a) % 12; if (ph < 0) ph += 12;
                float2 e = cE12[ph];
                float2 u = sU[mi * 12 + c];
                acc += u.x * e.x - u.y * e.y;
            }
            if (acc > 0.f) facc += wj * acc;
        }
        __syncthreads();
    }
    sred[tid] = facc;
    __syncthreads();
    for (int s = NT / 2; s > 0; s >>= 1) {
        if (tid < s) sred[tid] += sred[tid + s];
        __syncthreads();
    }
    if (tid == 0) {
        const float INTEG = 0.27415567780803774f;  // (2*pi/12)^2
        feat[b * 40 + o] = sred[0] * INTEG;
    }
}

// out[b][fo] = bias[fo] + sum_o feat[b][o] * w_out[fo][o]
__global__ void k_out(const float* __restrict__ feat, const float* __restrict__ w,
                      const float* __restrict__ bias, float* __restrict__ out) {
    int idx = blockIdx.x * blockDim.x + threadIdx.x;
    if (idx >= BT * 10) return;
    int fo = idx % 10, b = idx / 10;
    float acc = bias[fo];
    for (int o2 = 0; o2 < 40; ++o2) acc += feat[b * 40 + o2] * w[fo * 40 + o2];
    out[idx] = acc;
}

extern "C" void kernel_launch(void* const* d_in, const int* in_sizes, int n_in,
                              void* d_out, int out_size, void* d_ws, size_t ws_size,
                              hipStream_t stream) {
    (void)in_sizes; (void)n_in; (void)out_size; (void)ws_size;
    const float* x   = (const float*)d_in[0];
    const float* k1  = (const float*)d_in[1];
    const float* k2  = (const float*)d_in[2];
    const float* wO  = (const float*)d_in[3];
    const float* bO  = (const float*)d_in[4];
    float* out = (float*)d_out;

    float* ws = (float*)d_ws;
    const float2* cW60 = (const float2*)(ws + OFF_W60);
    const float2* cE20 = (const float2*)(ws + OFF_E20);
    const float2* cE12 = (const float2*)(ws + OFF_E12);
    const float*  cW2J = ws + OFF_W2J;
    const float*  cDM1 = ws + OFF_DM1;
    const float2* cY1B = (const float2*)(ws + OFF_Y1B);
    const float*  cD1  = ws + OFF_D1;
    const float*  cDM2 = ws + OFF_DM2;
    const float2* cY2B = (const float2*)(ws + OFF_Y2B);
    const float*  cD2  = ws + OFF_D2;

    float2* xh   = (float2*)(ws + OFF_END);          // 128*60*19
    float2* X    = xh + BT * 60 * 19;                // 100*128
    float2* Yk1  = X + 100 * BT;                     // 100*20
    float2* Yk2  = Yk1 + 100 * 20;                   // 286*40*20
    float2* X2   = Yk2 + 286 * 40 * 20;              // 286*128*20
    float*  feat = (float*)(X2 + 286 * BT * 20);     // 128*40

    k_init<<<(N_INIT + NT - 1) / NT, NT, 0, stream>>>(ws);
    k_dft_alpha<<<(BT * 60 * 19 + NT - 1) / NT, NT, 0, stream>>>(x, cW60, xh);
    k_X1<<<(100 * BT + NT - 1) / NT, NT, 0, stream>>>(xh, cDM1, X);
    k_Yk1<<<(100 * 20 + NT - 1) / NT, NT, 0, stream>>>(k1, cY1B, Yk1);
    k_Yk2<<<(286 * 40 * 20 + NT - 1) / NT, NT, 0, stream>>>(k2, cY2B, Yk2);
    k_stage1<<<BT * 20, NT, 0, stream>>>(X, Yk1, cD1, cDM2, cE20, X2);
    k_stage2<<<BT * 40, NT, 0, stream>>>(X2, Yk2, cD2, cE12, cW2J, feat);
    k_out<<<(BT * 10 + NT - 1) / NT, NT, 0, stream>>>(feat, wO, bO, out);
}

// Round 2
// 840.542 us; speedup vs baseline: 1.7671x; 1.7671x over previous
//
#include <hip/hip_runtime.h>
#include <cmath>

#define NT 256
#define BT 128

// ---------------- ws float-offsets for constant tables ----------------
#define OFF_W60   0          // 19*60 complex
#define OFF_E20   2280       // 20 complex (legacy, unused by kernels)
#define OFF_E12   2320       // 12 complex (legacy)
#define OFF_W2J   2344       // 12 floats
#define OFF_DM1   2356       // 100*60
#define OFF_Y1B   8356       // 100*24 complex
#define OFF_D1R   13156      // [j=20][flat=1330] d^l at beta1
#define OFF_DM2   39756      // [j=20][k2=286]  w1[j]*d^l(beta1_j)
#define OFF_Y2B   45476      // 286*192 complex
#define OFF_D2R   155300     // [j=12][flat=286] d^l at beta2
#define OFF_T19U  158732     // 20x19 complex [c][n] e^{+2pi i n c/20}
#define OFF_T11V  159492     // 11x20 complex [r][c] e^{-2pi i (r-5) c/20}
#define OFF_T12U  159932     // 12x11 complex [c][n] e^{+2pi i n c/12}
#define OFF_TABA  160196     // 1330 int packed (l | mi<<8 | ni<<16)
#define OFF_TABB  161526     // 286 int packed
#define OFF_END   161812
#define N_INIT    102596

__constant__ int c_ZB1[10] = {0,1,10,35,84,165,286,455,680,969};
__constant__ int c_ZB2[6]  = {0,1,10,35,84,165};

// ---------------- fp64 helpers for the init kernel ----------------
__device__ inline double dipow(double x, int e) {
    double r = 1.0;
    for (int i = 0; i < e; ++i) r *= x;
    return r;
}

__device__ double wigd(const double* F, int l, int mp, int m, double beta) {
    double cb = cos(beta * 0.5), sb = sin(beta * 0.5);
    int smin = m - mp; if (smin < 0) smin = 0;
    int smax = l + m;  if (l - mp < smax) smax = l - mp;
    double pref = sqrt(F[l+mp] * F[l-mp] * F[l+m] * F[l-m]);
    double sum = 0.0;
    for (int s = smin; s <= smax; ++s) {
        double t = pref / (F[l+m-s] * F[s] * F[mp-m+s] * F[l-mp-s]);
        t *= dipow(cb, 2*l + m - mp - 2*s) * dipow(sb, mp - m + 2*s);
        sum += ((mp - m + s) & 1) ? -t : t;
    }
    return sum;
}

__device__ double qwj(int bnd, int j) {
    const double PI = 3.14159265358979323846;
    double theta = PI * (2*j + 1) / (4.0 * bnd);
    double s = 0.0;
    for (int k = 0; k < bnd; ++k) s += sin(theta * (2*k + 1)) / (2*k + 1);
    return 2.0 / bnd * sin(theta) * s;
}

// ---------------- init ----------------
__global__ void k_init(float* __restrict__ ws) {
    int idx = blockIdx.x * blockDim.x + threadIdx.x;
    if (idx >= N_INIT) return;
    double F[20];
    F[0] = 1.0;
    #pragma unroll
    for (int i = 1; i < 20; ++i) F[i] = F[i-1] * i;
    const double PI = 3.14159265358979323846;

    if (idx < 1140) {                       // W60
        int r = idx / 60, a = idx % 60;
        double ang = -2.0 * PI * (double)((r - 9) * a) / 60.0;
        ws[OFF_W60 + 2*idx]     = (float)cos(ang);
        ws[OFF_W60 + 2*idx + 1] = (float)sin(ang);
    } else if (idx < 1160) {                // E20 (legacy)
        int t = idx - 1140;
        double ang = 2.0 * PI * t / 20.0;
        ws[OFF_E20 + 2*t]     = (float)cos(ang);
        ws[OFF_E20 + 2*t + 1] = (float)sin(ang);
    } else if (idx < 1172) {                // E12 (legacy)
        int t = idx - 1160;
        double ang = 2.0 * PI * t / 12.0;
        ws[OFF_E12 + 2*t]     = (float)cos(ang);
        ws[OFF_E12 + 2*t + 1] = (float)sin(ang);
    } else if (idx < 1184) {                // W2J
        int j = idx - 1172;
        ws[OFF_W2J + j] = (float)qwj(6, j);
    } else if (idx < 7184) {                // DM1[k][j]
        int e = idx - 1184; int k = e / 60, j = e % 60;
        int l = 0; while ((l + 1) * (l + 1) <= k) ++l;
        int m = k - l*l - l;
        double beta = PI * (2*j + 1) / 120.0;
        ws[OFF_DM1 + e] = (float)(qwj(30, j) * wigd(F, l, m, 0, beta));
    } else if (idx < 9584) {                // Y1B
        int e = idx - 7184; int k = e / 24, g = e % 24;
        int l = 0; while ((l + 1) * (l + 1) <= k) ++l;
        int m = k - l*l - l;
        int bi = g / 8, ai = g % 8;
        double beta  = (bi + 1) * (PI / 8.0) / 3.0;
        double alpha = 2.0 * PI * ai / 8.0;
        double d = wigd(F, l, m, 0, beta);
        double ph = -(double)m * alpha;
        ws[OFF_Y1B + 2*e]     = (float)(d * cos(ph));
        ws[OFF_Y1B + 2*e + 1] = (float)(d * sin(ph));
    } else if (idx < 36184) {               // D1R [j][flat]
        int e = idx - 9584; int j = e / 1330, t = e % 1330;
        int l = 0; while (l < 9 && t >= c_ZB1[l+1]) ++l;
        int L = 2*l + 1, loc = t - c_ZB1[l];
        int mi = loc / L, ni = loc % L;
        double beta = PI * (2*j + 1) / 40.0;
        ws[OFF_D1R + e] = (float)wigd(F, l, mi - l, ni - l, beta);
    } else if (idx < 41904) {               // DM2 [j][k2]
        int e = idx - 36184; int j = e / 286, k2 = e % 286;
        int l = 0; while (l < 5 && k2 >= c_ZB2[l+1]) ++l;
        int L = 2*l + 1, loc = k2 - c_ZB2[l];
        int mi = loc / L, ni = loc % L;
        double beta = PI * (2*j + 1) / 40.0;
        ws[OFF_DM2 + e] = (float)(qwj(10, j) * wigd(F, l, mi - l, ni - l, beta));
    } else if (idx < 96816) {               // Y2B
        int e = idx - 41904; int k2 = e / 192, g = e % 192;
        int l = 0; while (l < 5 && k2 >= c_ZB2[l+1]) ++l;
        int L = 2*l + 1, loc = k2 - c_ZB2[l];
        int m = loc / L - l, n = loc % L - l;
        int bi = g / 64, ai = (g / 8) % 8, ci = g % 8;
        double beta  = (bi + 1) * (PI / 8.0) / 3.0;
        double alpha = 2.0 * PI * ai / 8.0;
        double gamma = (-2.0 * PI + ci * (PI / 2.0)) - alpha;
        double d = wigd(F, l, m, n, beta);
        double ph = -((double)m * alpha + (double)n * gamma);
        ws[OFF_Y2B + 2*e]     = (float)(d * cos(ph));
        ws[OFF_Y2B + 2*e + 1] = (float)(d * sin(ph));
    } else if (idx < 100248) {              // D2R [j][flat]
        int e = idx - 96816; int j = e / 286, t = e % 286;
        int l = 0; while (l < 5 && t >= c_ZB2[l+1]) ++l;
        int L = 2*l + 1, loc = t - c_ZB2[l];
        int mi = loc / L, ni = loc % L;
        double beta = PI * (2*j + 1) / 24.0;
        ws[OFF_D2R + e] = (float)wigd(F, l, mi - l, ni - l, beta);
    } else if (idx < 100628) {              // T19U [c][n]
        int e = idx - 100248; int c = e / 19, n = e % 19 - 9;
        double ang = 2.0 * PI * (double)(n * c) / 20.0;
        ws[OFF_T19U + 2*e]     = (float)cos(ang);
        ws[OFF_T19U + 2*e + 1] = (float)sin(ang);
    } else if (idx < 100848) {              // T11V [r][c]
        int e = idx - 100628; int r = e / 20, c = e % 20;
        double ang = -2.0 * PI * (double)((r - 5) * c) / 20.0;
        ws[OFF_T11V + 2*e]     = (float)cos(ang);
        ws[OFF_T11V + 2*e + 1] = (float)sin(ang);
    } else if (idx < 100980) {              // T12U [c][n]
        int e = idx - 100848; int c = e / 11, n = e % 11 - 5;
        double ang = 2.0 * PI * (double)(n * c) / 12.0;
        ws[OFF_T12U + 2*e]     = (float)cos(ang);
        ws[OFF_T12U + 2*e + 1] = (float)sin(ang);
    } else if (idx < 102310) {              // TABA
        int t = idx - 100980;
        int l = 0; while (l < 9 && t >= c_ZB1[l+1]) ++l;
        int L = 2*l + 1, loc = t - c_ZB1[l];
        ((int*)ws)[OFF_TABA + t] = l | ((loc / L) << 8) | ((loc % L) << 16);
    } else {                                // TABB
        int t = idx - 102310;
        int l = 0; while (l < 5 && t >= c_ZB2[l+1]) ++l;
        int L = 2*l + 1, loc = t - c_ZB2[l];
        ((int*)ws)[OFF_TABB + t] = l | ((loc / L) << 8) | ((loc % L) << 16);
    }
}

// ---------------- small pipeline kernels ----------------
__global__ void k_dft_alpha(const float* __restrict__ x, const float2* __restrict__ W60,
                            float2* __restrict__ xh) {
    int idx = blockIdx.x * blockDim.x + threadIdx.x;
    if (idx >= BT * 60 * 19) return;
    int r = idx % 19;
    int j = (idx / 19) % 60;
    int b = idx / (19 * 60);
    const float* xr = x + (b * 60 + j) * 60;
    const float2* wr = W60 + r * 60;
    float re = 0.f, im = 0.f;
    for (int a = 0; a < 60; ++a) {
        float v = xr[a];
        float2 w = wr[a];
        re += v * w.x; im += v * w.y;
    }
    xh[idx] = make_float2(re * (1.f / 60.f), im * (1.f / 60.f));
}

__global__ void k_X1(const float2* __restrict__ xh, const float* __restrict__ DM1,
                     float2* __restrict__ X) {
    int idx = blockIdx.x * blockDim.x + threadIdx.x;
    if (idx >= 100 * BT) return;
    int b = idx % BT, k = idx / BT;
    int l = 0; while ((l + 1) * (l + 1) <= k) ++l;
    int r = (k - l*l - l) + 9;
    float re = 0.f, im = 0.f;
    for (int j = 0; j < 60; ++j) {
        float d = DM1[k * 60 + j];
        float2 v = xh[(b * 60 + j) * 19 + r];
        re += d * v.x; im += d * v.y;
    }
    X[k * BT + b] = make_float2(re, im);
}

__global__ void k_Yk1(const float* __restrict__ k1, const float2* __restrict__ Y1B,
                      float2* __restrict__ Yk1) {
    int idx = blockIdx.x * blockDim.x + threadIdx.x;
    if (idx >= 100 * 20) return;
    int o = idx % 20, k = idx / 20;
    float re = 0.f, im = 0.f;
    for (int g = 0; g < 24; ++g) {
        float2 y = Y1B[k * 24 + g];
        float w = k1[o * 24 + g];
        re += y.x * w; im += y.y * w;
    }
    const float SC1 = 0.20412414523193154f;  // 1/sqrt(24)
    Yk1[idx] = make_float2(re * SC1, im * SC1);
}

// Yk2 layout: [o][k2][i]
__global__ void k_Yk2(const float* __restrict__ k2in, const float2* __restrict__ Y2B,
                      float2* __restrict__ Yk2) {
    int idx = blockIdx.x * blockDim.x + threadIdx.x;
    if (idx >= 286 * 40 * 20) return;
    int i = idx % 20, o = (idx / 20) % 40, k = idx / 800;
    const float* kp = k2in + (i * 40 + o) * 192;
    const float2* yp = Y2B + k * 192;
    float re = 0.f, im = 0.f;
    for (int g = 0; g < 192; ++g) {
        float2 y = yp[g];
        float w = kp[g];
        re += y.x * w; im += y.y * w;
    }
    const float SC2 = 0.016137430609197573f; // 1/sqrt(192*20)
    Yk2[(o * 286 + k) * 20 + i] = make_float2(re * SC2, im * SC2);
}

// ---------------- stage 1: one block per (b,f1); 4 waves, wave w owns j = w+4*jj ----------------
// X2 layout: [b][k2][f1]  (f1 = i for stage2)
__global__ __launch_bounds__(NT) void k_stage1(
    const float2* __restrict__ X, const float2* __restrict__ Yk1,
    const float* __restrict__ gD1R, const float* __restrict__ gDM2,
    const float2* __restrict__ gT19, const float2* __restrict__ gT11,
    const int* __restrict__ gTABA, const int* __restrict__ gTABB,
    float2* __restrict__ X2g) {
    const int b = blockIdx.x % BT;
    const int f = blockIdx.x / BT;   // 0..19
    const int tid = threadIdx.x;
    const int wv = tid >> 6, lane = tid & 63;

    __shared__ __align__(16) float2 sZ[1330];
    __shared__ __align__(16) float2 sX2[286];
    __shared__ __align__(16) float2 sT19[400];   // [c][n], rows padded to 20
    __shared__ __align__(16) float2 sT11[220];   // [r][c], rows of 20
    __shared__ __align__(16) float2 sA[4][384];  // per-wave: S[19][20] | x1(400 f32) | G[121]
    __shared__ __align__(16) float2 sB[4][400];  // per-wave: U[20][20] | V[11][20]

    for (int t = tid; t < 380; t += NT) sT19[(t / 19) * 20 + (t % 19)] = gT19[t];
    for (int t = tid; t < 220; t += NT) sT11[t] = gT11[t];
    for (int t = tid; t < 286; t += NT) sX2[t] = make_float2(0.f, 0.f);
    for (int t = tid; t < 1330; t += NT) {
        int p = gTABA[t];
        int l = p & 255, mi = (p >> 8) & 255, ni = p >> 16;
        float2 a = X[(l*l + mi) * BT + b];
        float2 y = Yk1[(l*l + ni) * 20 + f];
        sZ[t] = make_float2(a.x * y.x + a.y * y.y, a.y * y.x - a.x * y.y);
    }
    __syncthreads();

    float2* S  = sA[wv];             // S[mi][ni], stride 20
    float2* U  = sB[wv];             // U[c][mi], stride 20
    float*  x1 = (float*)sA[wv];     // x1[a][c], stride 20
    float2* V  = sB[wv];             // V[n][a], stride 20
    float2* G  = sA[wv];             // G[m'][n'], stride 11

    for (int jj = 0; jj < 5; ++jj) {
        const int j = wv + 4 * jj;

        // ---- S[m][n] = sum_l (2l+1) d^l_j[m,n] Z[l,m,n]
        {
            const float* dp = gD1R + j * 1330;
            for (int t = lane; t < 361; t += 64) {
                int mi = t / 19, ni = t % 19;
                int m = mi - 9, n = ni - 9;
                int am = m < 0 ? -m : m, an = n < 0 ? -n : n;
                int lmin = am > an ? am : an;
                float re = 0.f, im = 0.f;
                for (int l = lmin; l < 10; ++l) {
                    int L = 2*l + 1;
                    int o = c_ZB1[l] + (m + l) * L + (n + l);
                    float dv = dp[o] * (float)L;
                    float2 z = sZ[o];
                    re += dv * z.x; im += dv * z.y;
                }
                S[mi * 20 + ni] = make_float2(re, im);
            }
        }
        __syncthreads();

        // ---- U[m][c] = sum_n S[m][n] T19[c][n]  (write transposed U[c][m])
        for (int t = lane; t < 380; t += 64) {
            int mi = t / 20, c = t % 20;
            const float4* sp = (const float4*)(S + mi * 20);
            const float4* tp = (const float4*)(sT19 + c * 20);
            float re = 0.f, im = 0.f;
            #pragma unroll
            for (int p = 0; p < 9; ++p) {
                float4 s = sp[p], w = tp[p];
                re += s.x * w.x - s.y * w.y + s.z * w.z - s.w * w.w;
                im += s.x * w.y + s.y * w.x + s.z * w.w + s.w * w.z;
            }
            float2 s1 = S[mi * 20 + 18], w1 = sT19[c * 20 + 18];
            re += s1.x * w1.x - s1.y * w1.y;
            im += s1.x * w1.y + s1.y * w1.x;
            U[c * 20 + mi] = make_float2(re, im);
        }
        __syncthreads();

        // ---- x1[a][c] = relu(Re sum_m U[m][c] T19[a][m])
        for (int t = lane; t < 400; t += 64) {
            int a = t / 20, c = t % 20;
            const float4* up = (const float4*)(U + c * 20);
            const float4* tp = (const float4*)(sT19 + a * 20);
            float acc = 0.f;
            #pragma unroll
            for (int p = 0; p < 9; ++p) {
                float4 u = up[p], w = tp[p];
                acc += u.x * w.x - u.y * w.y + u.z * w.z - u.w * w.w;
            }
            float2 u1 = U[c * 20 + 18], w1 = sT19[a * 20 + 18];
            acc += u1.x * w1.x - u1.y * w1.y;
            x1[a * 20 + c] = acc > 0.f ? acc : 0.f;
        }
        __syncthreads();

        // ---- V[a][n] = sum_c x1[a][c] T11[n][c]  (write V[n][a])
        for (int t = lane; t < 220; t += 64) {
            int n = t / 20, a = t % 20;
            const float4* xp = (const float4*)(x1 + a * 20);
            const float4* tp = (const float4*)(sT11 + n * 20);
            float re = 0.f, im = 0.f;
            #pragma unroll
            for (int p = 0; p < 5; ++p) {
                float4 xv = xp[p];
                float4 t01 = tp[2*p], t23 = tp[2*p + 1];
                re += xv.x * t01.x + xv.y * t01.z + xv.z * t23.x + xv.w * t23.z;
                im += xv.x * t01.y + xv.y * t01.w + xv.z * t23.y + xv.w * t23.w;
            }
            V[n * 20 + a] = make_float2(re, im);
        }
        __syncthreads();

        // ---- G[m][n] = sum_a V[a][n] T11[m][a]
        for (int t = lane; t < 121; t += 64) {
            int mi = t / 11, ni = t % 11;
            const float4* vp = (const float4*)(V + ni * 20);
            const float4* tp = (const float4*)(sT11 + mi * 20);
            float re = 0.f, im = 0.f;
            #pragma unroll
            for (int q = 0; q < 10; ++q) {
                float4 v = vp[q], w = tp[q];
                re += v.x * w.x - v.y * w.y + v.z * w.z - v.w * w.w;
                im += v.x * w.y + v.y * w.x + v.z * w.w + v.w * w.z;
            }
            G[t] = make_float2(re, im);
        }
        __syncthreads();

        // ---- X2[k2] += DM2[j][k2] * G[m(k2)][n(k2)]
        {
            const float* dmp = gDM2 + j * 286;
            for (int k2 = lane; k2 < 286; k2 += 64) {
                int p = gTABB[k2];
                int l = p & 255, mi = (p >> 8) & 255, ni = p >> 16;
                float dm = dmp[k2];
                float2 g = G[(mi - l + 5) * 11 + (ni - l + 5)];
                atomicAdd(&sX2[k2].x, dm * g.x);
                atomicAdd(&sX2[k2].y, dm * g.y);
            }
        }
        __syncthreads();
    }

    for (int t = tid; t < 286; t += NT) {
        float2 v = sX2[t];
        X2g[b * 5720 + t * 20 + f] = make_float2(v.x * (1.f / 400.f), v.y * (1.f / 400.f));
    }
}

// ---------------- stage 2: one block per (b,f2); Z via per-l LDS staging; 4 waves own j's ----------------
__global__ __launch_bounds__(NT) void k_stage2(
    const float2* __restrict__ X2g, const float2* __restrict__ Yk2,
    const float* __restrict__ gD2R, const float2* __restrict__ gT12,
    const float* __restrict__ gW2J, float* __restrict__ feat) {
    const int b = blockIdx.x % BT;
    const int o = blockIdx.x / BT;   // 0..39
    const int tid = threadIdx.x;
    const int wv = tid >> 6, lane = tid & 63;

    __shared__ __align__(16) float2 sAB[2][121 * 20];
    __shared__ __align__(16) float2 sZ[286];
    __shared__ __align__(16) float2 sT12[144];   // [c][n], rows padded to 12
    __shared__ __align__(16) float2 sS2[4][132]; // [mi][ni], rows padded to 12
    __shared__ __align__(16) float2 sU2[4][144]; // [c][mi], rows padded to 12
    __shared__ float sred[NT];

    for (int t = tid; t < 132; t += NT) sT12[(t / 11) * 12 + (t % 11)] = gT12[t];
    for (int t = tid; t < 286; t += NT) sZ[t] = make_float2(0.f, 0.f);

    // ---- Z[(l,m,n)] = sum_{k,i} X2[l,m,k][b][i] * conj(Yk2[o][l,n,k][i])
    for (int l = 0; l < 6; ++l) {
        int L = 2*l + 1, base = c_ZB2[l], sz = L * L * 20;
        const float2* Ag = X2g + b * 5720 + base * 20;
        const float2* Bg = Yk2 + o * 5720 + base * 20;
        for (int t = tid; t < sz; t += NT) { sAB[0][t] = Ag[t]; sAB[1][t] = Bg[t]; }
        __syncthreads();
        int items = L * L * 2;
        for (int t = tid; t < items; t += NT) {
            int h = t & 1, mn = t >> 1;
            int mi = mn / L, ni = mn % L;
            float re = 0.f, im = 0.f;
            for (int k = 0; k < L; ++k) {
                const float4* ap = (const float4*)(sAB[0] + (mi * L + k) * 20 + h * 10);
                const float4* bp = (const float4*)(sAB[1] + (ni * L + k) * 20 + h * 10);
                #pragma unroll
                for (int p = 0; p < 5; ++p) {
                    float4 a = ap[p], y = bp[p];
                    re += a.x * y.x + a.y * y.y + a.z * y.z + a.w * y.w;
                    im += a.y * y.x - a.x * y.y + a.w * y.z - a.z * y.w;
                }
            }
            atomicAdd(&sZ[base + mn].x, re);
            atomicAdd(&sZ[base + mn].y, im);
        }
        __syncthreads();
    }

    float2* S = sS2[wv];
    float2* U = sU2[wv];
    float facc = 0.f;

    for (int jj = 0; jj < 3; ++jj) {
        const int j = wv + 4 * jj;

        // ---- S[m][n] = sum_l (2l+1) d^l_j[m,n] Z[l,m,n]
        {
            const float* dp = gD2R + j * 286;
            for (int t = lane; t < 121; t += 64) {
                int mi = t / 11, ni = t % 11;
                int m = mi - 5, n = ni - 5;
                int am = m < 0 ? -m : m, an = n < 0 ? -n : n;
                int lmin = am > an ? am : an;
                float re = 0.f, im = 0.f;
                for (int l = lmin; l < 6; ++l) {
                    int L = 2*l + 1;
                    int off = c_ZB2[l] + (m + l) * L + (n + l);
                    float dv = dp[off] * (float)L;
                    float2 z = sZ[off];
                    re += dv * z.x; im += dv * z.y;
                }
                S[mi * 12 + ni] = make_float2(re, im);
            }
        }
        __syncthreads();

        // ---- U[m][c] = sum_n S[m][n] T12[c][n]  (write U[c][m])
        for (int t = lane; t < 132; t += 64) {
            int mi = t / 12, c = t % 12;
            const float4* sp = (const float4*)(S + mi * 12);
            const float4* tp = (const float4*)(sT12 + c * 12);
            float re = 0.f, im = 0.f;
            #pragma unroll
            for (int p = 0; p < 5; ++p) {
                float4 s = sp[p], w = tp[p];
                re += s.x * w.x - s.y * w.y + s.z * w.z - s.w * w.w;
                im += s.x * w.y + s.y * w.x + s.z * w.w + s.w * w.z;
            }
            float2 s1 = S[mi * 12 + 10], w1 = sT12[c * 12 + 10];
            re += s1.x * w1.x - s1.y * w1.y;
            im += s1.x * w1.y + s1.y * w1.x;
            U[c * 12 + mi] = make_float2(re, im);
        }
        __syncthreads();

        // ---- x2[a][c] = relu(Re sum_m U[m][c] T12[a][m]); integrate
        {
            float wj = gW2J[j];
            for (int t = lane; t < 144; t += 64) {
                int a = t / 12, c = t % 12;
                const float4* up = (const float4*)(U + c * 12);
                const float4* tp = (const float4*)(sT12 + a * 12);
                float acc = 0.f;
                #pragma unroll
                for (int p = 0; p < 5; ++p) {
                    float4 u = up[p], w = tp[p];
                    acc += u.x * w.x - u.y * w.y + u.z * w.z - u.w * w.w;
                }
                float2 u1 = U[c * 12 + 10], w1 = sT12[a * 12 + 10];
                acc += u1.x * w1.x - u1.y * w1.y;
                if (acc > 0.f) facc += wj * acc;
            }
        }
        __syncthreads();
    }

    sred[tid] = facc;
    __syncthreads();
    for (int s = NT / 2; s > 0; s >>= 1) {
        if (tid < s) sred[tid] += sred[tid + s];
        __syncthreads();
    }
    if (tid == 0) {
        const float INTEG = 0.27415567780803774f;  // (2*pi/12)^2
        feat[b * 40 + o] = sred[0] * INTEG;
    }
}

__global__ void k_out(const float* __restrict__ feat, const float* __restrict__ w,
                      const float* __restrict__ bias, float* __restrict__ out) {
    int idx = blockIdx.x * blockDim.x + threadIdx.x;
    if (idx >= BT * 10) return;
    int fo = idx % 10, b = idx / 10;
    float acc = bias[fo];
    for (int o2 = 0; o2 < 40; ++o2) acc += feat[b * 40 + o2] * w[fo * 40 + o2];
    out[idx] = acc;
}

extern "C" void kernel_launch(void* const* d_in, const int* in_sizes, int n_in,
                              void* d_out, int out_size, void* d_ws, size_t ws_size,
                              hipStream_t stream) {
    (void)in_sizes; (void)n_in; (void)out_size; (void)ws_size;
    const float* x   = (const float*)d_in[0];
    const float* k1  = (const float*)d_in[1];
    const float* k2  = (const float*)d_in[2];
    const float* wO  = (const float*)d_in[3];
    const float* bO  = (const float*)d_in[4];
    float* out = (float*)d_out;

    float* ws = (float*)d_ws;
    const float2* cW60 = (const float2*)(ws + OFF_W60);
    const float*  cW2J = ws + OFF_W2J;
    const float*  cDM1 = ws + OFF_DM1;
    const float2* cY1B = (const float2*)(ws + OFF_Y1B);
    const float*  gD1R = ws + OFF_D1R;
    const float*  gDM2 = ws + OFF_DM2;
    const float2* cY2B = (const float2*)(ws + OFF_Y2B);
    const float*  gD2R = ws + OFF_D2R;
    const float2* gT19 = (const float2*)(ws + OFF_T19U);
    const float2* gT11 = (const float2*)(ws + OFF_T11V);
    const float2* gT12 = (const float2*)(ws + OFF_T12U);
    const int*    gTABA = (const int*)(ws + OFF_TABA);
    const int*    gTABB = (const int*)(ws + OFF_TABB);

    float2* xh   = (float2*)(ws + OFF_END);          // 128*60*19
    float2* X    = xh + BT * 60 * 19;                // 100*128
    float2* Yk1  = X + 100 * BT;                     // 100*20
    float2* Yk2  = Yk1 + 100 * 20;                   // 40*286*20
    float2* X2   = Yk2 + 40 * 286 * 20;              // 128*286*20  [b][k2][i]
    float*  feat = (float*)(X2 + (size_t)BT * 5720); // 128*40

    k_init<<<(N_INIT + NT - 1) / NT, NT, 0, stream>>>(ws);
    k_dft_alpha<<<(BT * 60 * 19 + NT - 1) / NT, NT, 0, stream>>>(x, cW60, xh);
    k_X1<<<(100 * BT + NT - 1) / NT, NT, 0, stream>>>(xh, cDM1, X);
    k_Yk1<<<(100 * 20 + NT - 1) / NT, NT, 0, stream>>>(k1, cY1B, Yk1);
    k_Yk2<<<(286 * 40 * 20 + NT - 1) / NT, NT, 0, stream>>>(k2, cY2B, Yk2);
    k_stage1<<<BT * 20, NT, 0, stream>>>(X, Yk1, gD1R, gDM2, gT19, gT11, gTABA, gTABB, X2);
    k_stage2<<<BT * 40, NT, 0, stream>>>(X2, Yk2, gD2R, gT12, cW2J, feat);
    k_out<<<(BT * 10 + NT - 1) / NT, NT, 0, stream>>>(feat, wO, bO, out);
}

// Round 3
// 700.335 us; speedup vs baseline: 2.1209x; 1.2002x over previous
//
#include <hip/hip_runtime.h>
#include <cmath>

#define NT 256
#define BT 128

// ---------------- ws float-offsets for constant tables ----------------
#define OFF_W60   0          // 19*60 complex
#define OFF_E20   2280       // legacy
#define OFF_E12   2320       // legacy
#define OFF_W2J   2344       // 12 floats
#define OFF_DM1   2356       // 100*60
#define OFF_Y1B   8356       // 100*24 complex
#define OFF_D1R   13156      // [j=20][flat=1330] (2l+1)*d^l at beta1
#define OFF_DM2   39756      // [j=20][k2=286]  w1[j]*d^l(beta1_j)
#define OFF_Y2B   45476      // 286*192 complex
#define OFF_D2R   155300     // [j=12][flat=286] (2l+1)*d^l at beta2
#define OFF_T19U  158732     // 20x19 complex [c][n] e^{+2pi i n c/20}
#define OFF_T11V  159492     // 11x20 complex [r][c] e^{-2pi i (r-5) c/20}
#define OFF_T12U  159932     // 12x11 complex [c][n] e^{+2pi i n c/12}
#define OFF_TABA  160196     // 1330 int packed (l | mi<<8 | ni<<16)
#define OFF_TABB  161526     // 286 int packed
#define OFF_END   161812
#define N_INIT    102596

__constant__ int c_ZB1[10] = {0,1,10,35,84,165,286,455,680,969};
__constant__ int c_ZB2[6]  = {0,1,10,35,84,165};
__constant__ int c_BOFF[6] = {0,22,208,718,1712,3350};  // padded row offsets for k_Z2 LDS

// wave-local sync: per-wave LDS phase buffers only. lgkmcnt(0) guarantees all
// prior ds_write/ds_read complete; wave_barrier + memory clobber stops compiler
// from moving LDS ops across. No s_barrier -> waves proceed independently.
__device__ inline void wsync() {
    __asm__ volatile("" ::: "memory");
    __builtin_amdgcn_s_waitcnt(0xC07F);   // vmcnt=63, expcnt=7, lgkmcnt=0
    __builtin_amdgcn_wave_barrier();
    __asm__ volatile("" ::: "memory");
}

// ---------------- fp64 helpers for the init kernel ----------------
__device__ inline double dipow(double x, int e) {
    double r = 1.0;
    for (int i = 0; i < e; ++i) r *= x;
    return r;
}

__device__ double wigd(const double* F, int l, int mp, int m, double beta) {
    double cb = cos(beta * 0.5), sb = sin(beta * 0.5);
    int smin = m - mp; if (smin < 0) smin = 0;
    int smax = l + m;  if (l - mp < smax) smax = l - mp;
    double pref = sqrt(F[l+mp] * F[l-mp] * F[l+m] * F[l-m]);
    double sum = 0.0;
    for (int s = smin; s <= smax; ++s) {
        double t = pref / (F[l+m-s] * F[s] * F[mp-m+s] * F[l-mp-s]);
        t *= dipow(cb, 2*l + m - mp - 2*s) * dipow(sb, mp - m + 2*s);
        sum += ((mp - m + s) & 1) ? -t : t;
    }
    return sum;
}

__device__ double qwj(int bnd, int j) {
    const double PI = 3.14159265358979323846;
    double theta = PI * (2*j + 1) / (4.0 * bnd);
    double s = 0.0;
    for (int k = 0; k < bnd; ++k) s += sin(theta * (2*k + 1)) / (2*k + 1);
    return 2.0 / bnd * sin(theta) * s;
}

// ---------------- init ----------------
__global__ void k_init(float* __restrict__ ws) {
    int idx = blockIdx.x * blockDim.x + threadIdx.x;
    if (idx >= N_INIT) return;
    double F[20];
    F[0] = 1.0;
    #pragma unroll
    for (int i = 1; i < 20; ++i) F[i] = F[i-1] * i;
    const double PI = 3.14159265358979323846;

    if (idx < 1140) {                       // W60
        int r = idx / 60, a = idx % 60;
        double ang = -2.0 * PI * (double)((r - 9) * a) / 60.0;
        ws[OFF_W60 + 2*idx]     = (float)cos(ang);
        ws[OFF_W60 + 2*idx + 1] = (float)sin(ang);
    } else if (idx < 1160) {
        int t = idx - 1140;
        double ang = 2.0 * PI * t / 20.0;
        ws[OFF_E20 + 2*t]     = (float)cos(ang);
        ws[OFF_E20 + 2*t + 1] = (float)sin(ang);
    } else if (idx < 1172) {
        int t = idx - 1160;
        double ang = 2.0 * PI * t / 12.0;
        ws[OFF_E12 + 2*t]     = (float)cos(ang);
        ws[OFF_E12 + 2*t + 1] = (float)sin(ang);
    } else if (idx < 1184) {                // W2J
        int j = idx - 1172;
        ws[OFF_W2J + j] = (float)qwj(6, j);
    } else if (idx < 7184) {                // DM1[k][j]
        int e = idx - 1184; int k = e / 60, j = e % 60;
        int l = 0; while ((l + 1) * (l + 1) <= k) ++l;
        int m = k - l*l - l;
        double beta = PI * (2*j + 1) / 120.0;
        ws[OFF_DM1 + e] = (float)(qwj(30, j) * wigd(F, l, m, 0, beta));
    } else if (idx < 9584) {                // Y1B
        int e = idx - 7184; int k = e / 24, g = e % 24;
        int l = 0; while ((l + 1) * (l + 1) <= k) ++l;
        int m = k - l*l - l;
        int bi = g / 8, ai = g % 8;
        double beta  = (bi + 1) * (PI / 8.0) / 3.0;
        double alpha = 2.0 * PI * ai / 8.0;
        double d = wigd(F, l, m, 0, beta);
        double ph = -(double)m * alpha;
        ws[OFF_Y1B + 2*e]     = (float)(d * cos(ph));
        ws[OFF_Y1B + 2*e + 1] = (float)(d * sin(ph));
    } else if (idx < 36184) {               // D1R [j][flat], prescaled by (2l+1)
        int e = idx - 9584; int j = e / 1330, t = e % 1330;
        int l = 0; while (l < 9 && t >= c_ZB1[l+1]) ++l;
        int L = 2*l + 1, loc = t - c_ZB1[l];
        int mi = loc / L, ni = loc % L;
        double beta = PI * (2*j + 1) / 40.0;
        ws[OFF_D1R + e] = (float)((double)L * wigd(F, l, mi - l, ni - l, beta));
    } else if (idx < 41904) {               // DM2 [j][k2]
        int e = idx - 36184; int j = e / 286, k2 = e % 286;
        int l = 0; while (l < 5 && k2 >= c_ZB2[l+1]) ++l;
        int L = 2*l + 1, loc = k2 - c_ZB2[l];
        int mi = loc / L, ni = loc % L;
        double beta = PI * (2*j + 1) / 40.0;
        ws[OFF_DM2 + e] = (float)(qwj(10, j) * wigd(F, l, mi - l, ni - l, beta));
    } else if (idx < 96816) {               // Y2B
        int e = idx - 41904; int k2 = e / 192, g = e % 192;
        int l = 0; while (l < 5 && k2 >= c_ZB2[l+1]) ++l;
        int L = 2*l + 1, loc = k2 - c_ZB2[l];
        int m = loc / L - l, n = loc % L - l;
        int bi = g / 64, ai = (g / 8) % 8, ci = g % 8;
        double beta  = (bi + 1) * (PI / 8.0) / 3.0;
        double alpha = 2.0 * PI * ai / 8.0;
        double gamma = (-2.0 * PI + ci * (PI / 2.0)) - alpha;
        double d = wigd(F, l, m, n, beta);
        double ph = -((double)m * alpha + (double)n * gamma);
        ws[OFF_Y2B + 2*e]     = (float)(d * cos(ph));
        ws[OFF_Y2B + 2*e + 1] = (float)(d * sin(ph));
    } else if (idx < 100248) {              // D2R [j][flat], prescaled by (2l+1)
        int e = idx - 96816; int j = e / 286, t = e % 286;
        int l = 0; while (l < 5 && t >= c_ZB2[l+1]) ++l;
        int L = 2*l + 1, loc = t - c_ZB2[l];
        int mi = loc / L, ni = loc % L;
        double beta = PI * (2*j + 1) / 24.0;
        ws[OFF_D2R + e] = (float)((double)L * wigd(F, l, mi - l, ni - l, beta));
    } else if (idx < 100628) {              // T19U [c][n]
        int e = idx - 100248; int c = e / 19, n = e % 19 - 9;
        double ang = 2.0 * PI * (double)(n * c) / 20.0;
        ws[OFF_T19U + 2*e]     = (float)cos(ang);
        ws[OFF_T19U + 2*e + 1] = (float)sin(ang);
    } else if (idx < 100848) {              // T11V [r][c]
        int e = idx - 100628; int r = e / 20, c = e % 20;
        double ang = -2.0 * PI * (double)((r - 5) * c) / 20.0;
        ws[OFF_T11V + 2*e]     = (float)cos(ang);
        ws[OFF_T11V + 2*e + 1] = (float)sin(ang);
    } else if (idx < 100980) {              // T12U [c][n]
        int e = idx - 100848; int c = e / 11, n = e % 11 - 5;
        double ang = 2.0 * PI * (double)(n * c) / 12.0;
        ws[OFF_T12U + 2*e]     = (float)cos(ang);
        ws[OFF_T12U + 2*e + 1] = (float)sin(ang);
    } else if (idx < 102310) {              // TABA
        int t = idx - 100980;
        int l = 0; while (l < 9 && t >= c_ZB1[l+1]) ++l;
        int L = 2*l + 1, loc = t - c_ZB1[l];
        ((int*)ws)[OFF_TABA + t] = l | ((loc / L) << 8) | ((loc % L) << 16);
    } else {                                // TABB
        int t = idx - 102310;
        int l = 0; while (l < 5 && t >= c_ZB2[l+1]) ++l;
        int L = 2*l + 1, loc = t - c_ZB2[l];
        ((int*)ws)[OFF_TABB + t] = l | ((loc / L) << 8) | ((loc % L) << 16);
    }
}

// ---------------- small pipeline kernels ----------------
__global__ void k_dft_alpha(const float* __restrict__ x, const float2* __restrict__ W60,
                            float2* __restrict__ xh) {
    int idx = blockIdx.x * blockDim.x + threadIdx.x;
    if (idx >= BT * 60 * 19) return;
    int r = idx % 19;
    int j = (idx / 19) % 60;
    int b = idx / (19 * 60);
    const float* xr = x + (b * 60 + j) * 60;
    const float2* wr = W60 + r * 60;
    float re = 0.f, im = 0.f;
    for (int a = 0; a < 60; ++a) {
        float v = xr[a];
        float2 w = wr[a];
        re += v * w.x; im += v * w.y;
    }
    xh[idx] = make_float2(re * (1.f / 60.f), im * (1.f / 60.f));
}

__global__ void k_X1(const float2* __restrict__ xh, const float* __restrict__ DM1,
                     float2* __restrict__ X) {
    int idx = blockIdx.x * blockDim.x + threadIdx.x;
    if (idx >= 100 * BT) return;
    int b = idx % BT, k = idx / BT;
    int l = 0; while ((l + 1) * (l + 1) <= k) ++l;
    int r = (k - l*l - l) + 9;
    float re = 0.f, im = 0.f;
    for (int j = 0; j < 60; ++j) {
        float d = DM1[k * 60 + j];
        float2 v = xh[(b * 60 + j) * 19 + r];
        re += d * v.x; im += d * v.y;
    }
    X[k * BT + b] = make_float2(re, im);
}

__global__ void k_Yk1(const float* __restrict__ k1, const float2* __restrict__ Y1B,
                      float2* __restrict__ Yk1) {
    int idx = blockIdx.x * blockDim.x + threadIdx.x;
    if (idx >= 100 * 20) return;
    int o = idx % 20, k = idx / 20;
    float re = 0.f, im = 0.f;
    for (int g = 0; g < 24; ++g) {
        float2 y = Y1B[k * 24 + g];
        float w = k1[o * 24 + g];
        re += y.x * w; im += y.y * w;
    }
    const float SC1 = 0.20412414523193154f;  // 1/sqrt(24)
    Yk1[idx] = make_float2(re * SC1, im * SC1);
}

// Yk2 layout: [o][k2][i]; one block per k2, Y2B row staged in LDS
__global__ __launch_bounds__(NT) void k_Yk2(const float* __restrict__ k2in,
                                            const float2* __restrict__ Y2B,
                                            float2* __restrict__ Yk2) {
    const int k = blockIdx.x;      // 0..285
    const int tid = threadIdx.x;
    __shared__ __align__(16) float2 sY[192];
    for (int t = tid; t < 192; t += NT) sY[t] = Y2B[k * 192 + t];
    __syncthreads();
    const float4* sY4 = (const float4*)sY;
    const float SC2 = 0.016137430609197573f; // 1/sqrt(192*20)
    for (int t = tid; t < 800; t += NT) {
        int o = t / 20, i = t % 20;
        const float4* kp = (const float4*)(k2in + (i * 40 + o) * 192);
        float re = 0.f, im = 0.f;
        #pragma unroll 4
        for (int p = 0; p < 48; ++p) {
            float4 w = kp[p];
            float4 y01 = sY4[2*p], y23 = sY4[2*p + 1];
            re += w.x * y01.x + w.y * y01.z + w.z * y23.x + w.w * y23.z;
            im += w.x * y01.y + w.y * y01.w + w.z * y23.y + w.w * y23.w;
        }
        Yk2[(o * 286 + k) * 20 + i] = make_float2(re * SC2, im * SC2);
    }
}

// ---------------- stage 1: one block per (b,f1); wave-autonomous j-slices ----------------
// X2 layout: [b][k2][f1]
__global__ __launch_bounds__(NT) void k_stage1(
    const float2* __restrict__ X, const float2* __restrict__ Yk1,
    const float* __restrict__ gD1R, const float* __restrict__ gDM2,
    const float2* __restrict__ gT19, const float2* __restrict__ gT11,
    const int* __restrict__ gTABA, const int* __restrict__ gTABB,
    float2* __restrict__ X2g) {
    const int b = blockIdx.x % BT;
    const int f = blockIdx.x / BT;   // 0..19
    const int tid = threadIdx.x;
    const int wv = tid >> 6, lane = tid & 63;

    __shared__ __align__(16) float2 sZ[1330];
    __shared__ __align__(16) float2 sX2w[4][286];
    __shared__ __align__(16) float2 sT19[440];   // [c][n], stride 22
    __shared__ __align__(16) float2 sT11[220];   // [r][c], stride 20
    __shared__ __align__(16) float2 sA[4][424];  // per-wave: S(19x22) | x1(400f) | G(121)
    __shared__ __align__(16) float2 sB[4][440];  // per-wave: U(20x22) | V(11x22)

    for (int t = tid; t < 380; t += NT) sT19[(t / 19) * 22 + (t % 19)] = gT19[t];
    for (int t = tid; t < 220; t += NT) sT11[t] = gT11[t];
    for (int t = tid; t < 286; t += NT) {
        sX2w[0][t] = make_float2(0.f, 0.f); sX2w[1][t] = make_float2(0.f, 0.f);
        sX2w[2][t] = make_float2(0.f, 0.f); sX2w[3][t] = make_float2(0.f, 0.f);
    }
    for (int t = tid; t < 1330; t += NT) {
        int p = gTABA[t];
        int l = p & 255, mi = (p >> 8) & 255, ni = p >> 16;
        float2 a = X[(l*l + mi) * BT + b];
        float2 y = Yk1[(l*l + ni) * 20 + f];
        sZ[t] = make_float2(a.x * y.x + a.y * y.y, a.y * y.x - a.x * y.y);
    }
    __syncthreads();

    float2* S   = sA[wv];            // [mi][ni] stride 22
    float2* U   = sB[wv];            // [c][mi] stride 22
    float*  x1  = (float*)sA[wv];    // [a][c] stride 20 (floats)
    float2* V   = sB[wv];            // [n][a] stride 22
    float2* G   = sA[wv];            // [m'][n'] stride 11
    float2* myX2 = sX2w[wv];

    for (int jj = 0; jj < 5; ++jj) {
        const int j = wv + 4 * jj;

        // ---- S[m][n] = sum_l (2l+1)d^l_j[m,n] Z[l,m,n]  (D1R prescaled)
        {
            const float* dp = gD1R + j * 1330;
            for (int t = lane; t < 361; t += 64) {
                int mi = t / 19, ni = t % 19;
                int m = mi - 9, n = ni - 9;
                int am = m < 0 ? -m : m, an = n < 0 ? -n : n;
                int lmin = am > an ? am : an;
                float re = 0.f, im = 0.f;
                for (int l = lmin; l < 10; ++l) {
                    int L = 2*l + 1;
                    int o = c_ZB1[l] + (m + l) * L + (n + l);
                    float dv = dp[o];
                    float2 z = sZ[o];
                    re += dv * z.x; im += dv * z.y;
                }
                S[mi * 22 + ni] = make_float2(re, im);
            }
        }
        wsync();

        // ---- U[m][c] = sum_n S[m][n] T19[c][n]  (write U[c][m])
        for (int t = lane; t < 380; t += 64) {
            int mi = t / 20, c = t % 20;
            const float4* sp = (const float4*)(S + mi * 22);
            const float4* tp = (const float4*)(sT19 + c * 22);
            float re = 0.f, im = 0.f;
            #pragma unroll
            for (int p = 0; p < 9; ++p) {
                float4 s = sp[p], w = tp[p];
                re += s.x * w.x - s.y * w.y + s.z * w.z - s.w * w.w;
                im += s.x * w.y + s.y * w.x + s.z * w.w + s.w * w.z;
            }
            float2 s1 = S[mi * 22 + 18], w1 = sT19[c * 22 + 18];
            re += s1.x * w1.x - s1.y * w1.y;
            im += s1.x * w1.y + s1.y * w1.x;
            U[c * 22 + mi] = make_float2(re, im);
        }
        wsync();

        // ---- x1[a][c] = relu(Re sum_m U[m][c] T19[a][m])
        for (int t = lane; t < 400; t += 64) {
            int a = t / 20, c = t % 20;
            const float4* up = (const float4*)(U + c * 22);
            const float4* tp = (const float4*)(sT19 + a * 22);
            float acc = 0.f;
            #pragma unroll
            for (int p = 0; p < 9; ++p) {
                float4 u = up[p], w = tp[p];
                acc += u.x * w.x - u.y * w.y + u.z * w.z - u.w * w.w;
            }
            float2 u1 = U[c * 22 + 18], w1 = sT19[a * 22 + 18];
            acc += u1.x * w1.x - u1.y * w1.y;
            x1[a * 20 + c] = acc > 0.f ? acc : 0.f;
        }
        wsync();

        // ---- V[a][n] = sum_c x1[a][c] T11[n][c]  (write V[n][a])
        for (int t = lane; t < 220; t += 64) {
            int n = t / 20, a = t % 20;
            const float4* xp = (const float4*)(x1 + a * 20);
            const float4* tp = (const float4*)(sT11 + n * 20);
            float re = 0.f, im = 0.f;
            #pragma unroll
            for (int p = 0; p < 5; ++p) {
                float4 xv = xp[p];
                float4 t01 = tp[2*p], t23 = tp[2*p + 1];
                re += xv.x * t01.x + xv.y * t01.z + xv.z * t23.x + xv.w * t23.z;
                im += xv.x * t01.y + xv.y * t01.w + xv.z * t23.y + xv.w * t23.w;
            }
            V[n * 22 + a] = make_float2(re, im);
        }
        wsync();

        // ---- G[m][n] = sum_a V[a][n] T11[m][a]
        for (int t = lane; t < 121; t += 64) {
            int mi = t / 11, ni = t % 11;
            const float4* vp = (const float4*)(V + ni * 22);
            const float4* tp = (const float4*)(sT11 + mi * 20);
            float re = 0.f, im = 0.f;
            #pragma unroll
            for (int q = 0; q < 10; ++q) {
                float4 v = vp[q], w = tp[q];
                re += v.x * w.x - v.y * w.y + v.z * w.z - v.w * w.w;
                im += v.x * w.y + v.y * w.x + v.z * w.w + v.w * w.z;
            }
            G[t] = make_float2(re, im);
        }
        wsync();

        // ---- X2w[k2] += DM2[j][k2] * G[...]
        {
            const float* dmp = gDM2 + j * 286;
            for (int k2 = lane; k2 < 286; k2 += 64) {
                int p = gTABB[k2];
                int l = p & 255, mi = (p >> 8) & 255, ni = p >> 16;
                float dm = dmp[k2];
                float2 g = G[(mi - l + 5) * 11 + (ni - l + 5)];
                myX2[k2].x += dm * g.x;
                myX2[k2].y += dm * g.y;
            }
        }
        wsync();
    }
    __syncthreads();

    for (int t = tid; t < 286; t += NT) {
        float2 v0 = sX2w[0][t], v1 = sX2w[1][t], v2 = sX2w[2][t], v3 = sX2w[3][t];
        X2g[b * 5720 + t * 20 + f] =
            make_float2((v0.x + v1.x + v2.x + v3.x) * (1.f / 400.f),
                        (v0.y + v1.y + v2.y + v3.y) * (1.f / 400.f));
    }
}

// ---------------- stage 2a: Z[b][o][k2] = sum_{k,i} A . conj(B) ----------------
// block = (o, b-tile of 16); Yk2[o] staged in LDS with padded rows
__global__ __launch_bounds__(NT) void k_Z2(
    const float2* __restrict__ X2g, const float2* __restrict__ Yk2,
    const int* __restrict__ gTABB, float2* __restrict__ Z2g) {
    const int bt = blockIdx.x & 7;        // 0..7
    const int o  = blockIdx.x >> 3;       // 0..39
    const int b0 = bt * 16;
    const int tid = threadIdx.x;

    __shared__ __align__(16) float2 sB[5792];

    const float2* Bg = Yk2 + o * 5720;
    for (int e = tid; e < 5720; e += NT) {
        int k2 = e / 20, i = e % 20;
        int p = gTABB[k2];
        int l = p & 255, r = (p >> 8) & 255, kk = p >> 16;
        sB[c_BOFF[l] + r * (40 * l + 22) + kk * 20 + i] = Bg[e];
    }
    __syncthreads();

    for (int q = tid; q < 16 * 286; q += NT) {
        int b_local = q / 286, t = q % 286;
        int p = gTABB[t];
        int l = p & 255, mi = (p >> 8) & 255, ni = p >> 16;
        int L = 2 * l + 1;
        const float4* ap = (const float4*)(X2g + (size_t)(b0 + b_local) * 5720
                                           + (c_ZB2[l] + mi * L) * 20);
        const float4* bp = (const float4*)(sB + c_BOFF[l] + ni * (40 * l + 22));
        float re = 0.f, im = 0.f;
        int n4 = 10 * L;
        for (int p4 = 0; p4 < n4; ++p4) {
            float4 a = ap[p4], y = bp[p4];
            re += a.x * y.x + a.y * y.y + a.z * y.z + a.w * y.w;
            im += a.y * y.x - a.x * y.y + a.w * y.z - a.z * y.w;
        }
        Z2g[((size_t)(b0 + b_local) * 40 + o) * 286 + t] = make_float2(re, im);
    }
}

// ---------------- stage 2b: per (b,o): j-loop + integrate ----------------
__global__ __launch_bounds__(NT) void k_stage2b(
    const float2* __restrict__ Z2g, const float* __restrict__ gD2R,
    const float2* __restrict__ gT12, const float* __restrict__ gW2J,
    float* __restrict__ feat) {
    const int b = blockIdx.x % BT;
    const int o = blockIdx.x / BT;   // 0..39
    const int tid = threadIdx.x;
    const int wv = tid >> 6, lane = tid & 63;

    __shared__ __align__(16) float2 sZb[286];
    __shared__ __align__(16) float2 sT12[168];   // [c][n], stride 14
    __shared__ __align__(16) float2 sS[4][154];  // [mi][ni], stride 14
    __shared__ __align__(16) float2 sU[4][168];  // [c][mi], stride 14
    __shared__ float sredw[4];

    const float2* Zr = Z2g + ((size_t)b * 40 + o) * 286;
    for (int t = tid; t < 286; t += NT) sZb[t] = Zr[t];
    for (int t = tid; t < 132; t += NT) sT12[(t / 11) * 14 + (t % 11)] = gT12[t];
    __syncthreads();

    float2* S = sS[wv];
    float2* U = sU[wv];
    float facc = 0.f;

    for (int jj = 0; jj < 3; ++jj) {
        const int j = wv + 4 * jj;

        // ---- S[m][n] = sum_l (2l+1)d^l_j[m,n] Z[l,m,n]  (D2R prescaled)
        {
            const float* dp = gD2R + j * 286;
            for (int t = lane; t < 121; t += 64) {
                int mi = t / 11, ni = t % 11;
                int m = mi - 5, n = ni - 5;
                int am = m < 0 ? -m : m, an = n < 0 ? -n : n;
                int lmin = am > an ? am : an;
                float re = 0.f, im = 0.f;
                for (int l = lmin; l < 6; ++l) {
                    int L = 2*l + 1;
                    int off = c_ZB2[l] + (m + l) * L + (n + l);
                    float dv = dp[off];
                    float2 z = sZb[off];
                    re += dv * z.x; im += dv * z.y;
                }
                S[mi * 14 + ni] = make_float2(re, im);
            }
        }
        wsync();

        // ---- U[m][c] = sum_n S[m][n] T12[c][n]  (write U[c][m])
        for (int t = lane; t < 132; t += 64) {
            int mi = t / 12, c = t % 12;
            const float4* sp = (const float4*)(S + mi * 14);
            const float4* tp = (const float4*)(sT12 + c * 14);
            float re = 0.f, im = 0.f;
            #pragma unroll
            for (int p = 0; p < 5; ++p) {
                float4 s = sp[p], w = tp[p];
                re += s.x * w.x - s.y * w.y + s.z * w.z - s.w * w.w;
                im += s.x * w.y + s.y * w.x + s.z * w.w + s.w * w.z;
            }
            float2 s1 = S[mi * 14 + 10], w1 = sT12[c * 14 + 10];
            re += s1.x * w1.x - s1.y * w1.y;
            im += s1.x * w1.y + s1.y * w1.x;
            U[c * 14 + mi] = make_float2(re, im);
        }
        wsync();

        // ---- x2[a][c] = relu(Re sum_m U[m][c] T12[a][m]); integrate
        {
            float wj = gW2J[j];
            for (int t = lane; t < 144; t += 64) {
                int a = t / 12, c = t % 12;
                const float4* up = (const float4*)(U + c * 14);
                const float4* tp = (const float4*)(sT12 + a * 14);
                float acc = 0.f;
                #pragma unroll
                for (int p = 0; p < 5; ++p) {
                    float4 u = up[p], w = tp[p];
                    acc += u.x * w.x - u.y * w.y + u.z * w.z - u.w * w.w;
                }
                float2 u1 = U[c * 14 + 10], w1 = sT12[a * 14 + 10];
                acc += u1.x * w1.x - u1.y * w1.y;
                if (acc > 0.f) facc += wj * acc;
            }
        }
        wsync();
    }

    // wave reduce, then cross-wave
    #pragma unroll
    for (int d = 32; d > 0; d >>= 1) facc += __shfl_down(facc, d, 64);
    if (lane == 0) sredw[wv] = facc;
    __syncthreads();
    if (tid == 0) {
        const float INTEG = 0.27415567780803774f;  // (2*pi/12)^2
        feat[b * 40 + o] = (sredw[0] + sredw[1] + sredw[2] + sredw[3]) * INTEG;
    }
}

__global__ void k_out(const float* __restrict__ feat, const float* __restrict__ w,
                      const float* __restrict__ bias, float* __restrict__ out) {
    int idx = blockIdx.x * blockDim.x + threadIdx.x;
    if (idx >= BT * 10) return;
    int fo = idx % 10, b = idx / 10;
    float acc = bias[fo];
    for (int o2 = 0; o2 < 40; ++o2) acc += feat[b * 40 + o2] * w[fo * 40 + o2];
    out[idx] = acc;
}

extern "C" void kernel_launch(void* const* d_in, const int* in_sizes, int n_in,
                              void* d_out, int out_size, void* d_ws, size_t ws_size,
                              hipStream_t stream) {
    (void)in_sizes; (void)n_in; (void)out_size; (void)ws_size;
    const float* x   = (const float*)d_in[0];
    const float* k1  = (const float*)d_in[1];
    const float* k2  = (const float*)d_in[2];
    const float* wO  = (const float*)d_in[3];
    const float* bO  = (const float*)d_in[4];
    float* out = (float*)d_out;

    float* ws = (float*)d_ws;
    const float2* cW60 = (const float2*)(ws + OFF_W60);
    const float*  cW2J = ws + OFF_W2J;
    const float*  cDM1 = ws + OFF_DM1;
    const float2* cY1B = (const float2*)(ws + OFF_Y1B);
    const float*  gD1R = ws + OFF_D1R;
    const float*  gDM2 = ws + OFF_DM2;
    const float2* cY2B = (const float2*)(ws + OFF_Y2B);
    const float*  gD2R = ws + OFF_D2R;
    const float2* gT19 = (const float2*)(ws + OFF_T19U);
    const float2* gT11 = (const float2*)(ws + OFF_T11V);
    const float2* gT12 = (const float2*)(ws + OFF_T12U);
    const int*    gTABA = (const int*)(ws + OFF_TABA);
    const int*    gTABB = (const int*)(ws + OFF_TABB);

    float2* xh   = (float2*)(ws + OFF_END);          // 128*60*19
    float2* X    = xh + BT * 60 * 19;                // 100*128
    float2* Yk1  = X + 100 * BT;                     // 100*20
    float2* Yk2  = Yk1 + 100 * 20;                   // 40*286*20
    float2* X2   = Yk2 + 40 * 286 * 20;              // 128*286*20  [b][k2][i]
    float*  feat = (float*)(X2 + (size_t)BT * 5720); // 128*40
    float2* Z2   = (float2*)(feat + BT * 40);        // 128*40*286

    k_init<<<(N_INIT + NT - 1) / NT, NT, 0, stream>>>(ws);
    k_dft_alpha<<<(BT * 60 * 19 + NT - 1) / NT, NT, 0, stream>>>(x, cW60, xh);
    k_X1<<<(100 * BT + NT - 1) / NT, NT, 0, stream>>>(xh, cDM1, X);
    k_Yk1<<<(100 * 20 + NT - 1) / NT, NT, 0, stream>>>(k1, cY1B, Yk1);
    k_Yk2<<<286, NT, 0, stream>>>(k2, cY2B, Yk2);
    k_stage1<<<BT * 20, NT, 0, stream>>>(X, Yk1, gD1R, gDM2, gT19, gT11, gTABA, gTABB, X2);
    k_Z2<<<320, NT, 0, stream>>>(X2, Yk2, gTABB, Z2);
    k_stage2b<<<BT * 40, NT, 0, stream>>>(Z2, gD2R, gT12, cW2J, feat);
    k_out<<<(BT * 10 + NT - 1) / NT, NT, 0, stream>>>(feat, wO, bO, out);
}